// Round 3
// baseline (307.515 us; speedup 1.0000x reference)
//
#include <hip/hip_runtime.h>
#include <math.h>

#define NN   32768
#define EE   524288
#define ETOT (EE + NN)
#define BB   32
#define NPG  1024
#define KK   512
#define INC  128
#define HID  64
#define NH   4
#define CC   256
#define SLOPE 0.2f

// ---------------- GEMM1: h[N,256] = x[N,128] @ W[128,256] ----------------
// 128x128 block tile, 8x8 micro-tile (VALU-bound: 128 FMA-cyc vs ~70 LDS-cyc
// per k-iter). Per-element k order is ascending 0..127 exactly as before ->
// bit-identical h (top-k selection safety).
__global__ __launch_bounds__(256) void gemm1_kernel(const float* __restrict__ x,
                                                    const float* __restrict__ W,
                                                    float* __restrict__ h) {
  __shared__ float As[128][65];   // pad 65: column reads conflict-free
  __shared__ float Bs[64][128];
  const int n0 = blockIdx.x * 128;
  const int c0 = blockIdx.y * 128;
  const int tid = threadIdx.x;
  const int rowg = tid >> 4;      // 0..15
  const int colg = tid & 15;      // 0..15
  const int lr = tid >> 4, lq = tid & 15;
  float acc[8][8] = {};
  for (int kc = 0; kc < 2; ++kc) {
    const int k0 = kc * 64;
#pragma unroll
    for (int p = 0; p < 8; ++p) {     // A: 128 rows x 64 k
      int row = p * 16 + lr;
      float4 v = *(const float4*)(x + (size_t)(n0 + row) * INC + k0 + lq * 4);
      As[row][lq * 4 + 0] = v.x; As[row][lq * 4 + 1] = v.y;
      As[row][lq * 4 + 2] = v.z; As[row][lq * 4 + 3] = v.w;
    }
#pragma unroll
    for (int p = 0; p < 8; ++p) {     // B: 64 k x 128 c
      int krow = (p & 3) * 16 + lr;
      int coff = (p >> 2) * 64 + lq * 4;
      *(float4*)(&Bs[krow][coff]) =
          *(const float4*)(W + (size_t)(k0 + krow) * CC + c0 + coff);
    }
    __syncthreads();
#pragma unroll
    for (int k = 0; k < 64; ++k) {
      float a[8];
#pragma unroll
      for (int i = 0; i < 8; ++i) a[i] = As[rowg * 8 + i][k];
      float4 b0 = *(const float4*)(&Bs[k][colg * 8]);
      float4 b1 = *(const float4*)(&Bs[k][colg * 8 + 4]);
#pragma unroll
      for (int i = 0; i < 8; ++i) {
        acc[i][0] += a[i] * b0.x; acc[i][1] += a[i] * b0.y;
        acc[i][2] += a[i] * b0.z; acc[i][3] += a[i] * b0.w;
        acc[i][4] += a[i] * b1.x; acc[i][5] += a[i] * b1.y;
        acc[i][6] += a[i] * b1.z; acc[i][7] += a[i] * b1.w;
      }
    }
    __syncthreads();
  }
#pragma unroll
  for (int i = 0; i < 8; ++i) {
    float* hp = h + (size_t)(n0 + rowg * 8 + i) * CC + c0 + colg * 8;
    *(float4*)(hp)     = make_float4(acc[i][0], acc[i][1], acc[i][2], acc[i][3]);
    *(float4*)(hp + 4) = make_float4(acc[i][4], acc[i][5], acc[i][6], acc[i][7]);
  }
}

// ---------------- GEMM2: xl[N,64] = outg[N,256] @ W_lin[256,64] + b_lin ----------------
__global__ __launch_bounds__(256) void gemm2_kernel(const float* __restrict__ A,
                                                    const float* __restrict__ Wl,
                                                    const float* __restrict__ bl,
                                                    float* __restrict__ xl) {
  __shared__ float As[128][65];
  __shared__ float Bs[64][64];
  const int n0 = blockIdx.x * 128;
  const int tid = threadIdx.x;
  const int rowg = tid >> 3, colg = tid & 7;
  const int lr = tid >> 4, lq = tid & 15;
  float acc[4][8] = {};
  for (int kc = 0; kc < 4; ++kc) {
    const int k0 = kc * 64;
#pragma unroll
    for (int p = 0; p < 8; ++p) {
      int row = p * 16 + lr;
      float4 v = *(const float4*)(A + (size_t)(n0 + row) * CC + k0 + lq * 4);
      As[row][lq * 4 + 0] = v.x; As[row][lq * 4 + 1] = v.y;
      As[row][lq * 4 + 2] = v.z; As[row][lq * 4 + 3] = v.w;
    }
#pragma unroll
    for (int p = 0; p < 4; ++p) {
      int krow = p * 16 + lr;
      *(float4*)(&Bs[krow][lq * 4]) =
          *(const float4*)(Wl + (size_t)(k0 + krow) * HID + lq * 4);
    }
    __syncthreads();
#pragma unroll
    for (int k = 0; k < 64; ++k) {
      float4 b0 = *(const float4*)(&Bs[k][colg * 8]);
      float4 b1 = *(const float4*)(&Bs[k][colg * 8 + 4]);
#pragma unroll
      for (int i = 0; i < 4; ++i) {
        float a = As[rowg * 4 + i][k];
        acc[i][0] += a * b0.x; acc[i][1] += a * b0.y;
        acc[i][2] += a * b0.z; acc[i][3] += a * b0.w;
        acc[i][4] += a * b1.x; acc[i][5] += a * b1.y;
        acc[i][6] += a * b1.z; acc[i][7] += a * b1.w;
      }
    }
    __syncthreads();
  }
  const float4 bv0 = *(const float4*)(bl + colg * 8);
  const float4 bv1 = *(const float4*)(bl + colg * 8 + 4);
#pragma unroll
  for (int i = 0; i < 4; ++i) {
    float* xp = xl + (size_t)(n0 + rowg * 4 + i) * HID + colg * 8;
    *(float4*)(xp)     = make_float4(acc[i][0] + bv0.x, acc[i][1] + bv0.y,
                                     acc[i][2] + bv0.z, acc[i][3] + bv0.w);
    *(float4*)(xp + 4) = make_float4(acc[i][4] + bv1.x, acc[i][5] + bv1.y,
                                     acc[i][6] + bv1.z, acc[i][7] + bv1.w);
  }
}

// ---------------- per-node attention logits (order-preserving) ----------------
__global__ __launch_bounds__(256) void al_kernel(const float* __restrict__ h,
                                                 const float* __restrict__ a_src,
                                                 const float* __restrict__ a_dst,
                                                 float* __restrict__ al_s,
                                                 float* __restrict__ al_d) {
  const int lane = threadIdx.x & 63;
  const int n = blockIdx.x * 4 + (threadIdx.x >> 6);
  const float* hr = h + (size_t)n * CC;
#pragma unroll
  for (int hd = 0; hd < NH; ++hd) {
    float hv = hr[hd * 64 + lane];
    float vs = hv * a_src[hd * 64 + lane];
    float vd = hv * a_dst[hd * 64 + lane];
#pragma unroll
    for (int off = 32; off > 0; off >>= 1) {
      vs += __shfl_down(vs, off);
      vd += __shfl_down(vd, off);
    }
    if (lane == 0) {
      al_s[n * NH + hd] = vs;
      al_d[n * NH + hd] = vd;
    }
  }
}

// ---------------- CSR build (by dst, self-loops included) ----------------
__global__ void count_kernel(const int* __restrict__ ei, int* __restrict__ cnt) {
  int e = blockIdx.x * 256 + threadIdx.x;
  if (e >= ETOT) return;
  int d = (e < EE) ? ei[EE + e] : (e - EE);
  atomicAdd(&cnt[d], 1);
}

__global__ __launch_bounds__(1024) void scan_kernel(const int* __restrict__ cnt,
                                                    int* __restrict__ row_ptr) {
  __shared__ int sums[1024];
  const int t = threadIdx.x;
  int local[32];
  int s = 0;
  const int base = t * 32;
#pragma unroll
  for (int i = 0; i < 32; ++i) { local[i] = s; s += cnt[base + i]; }
  sums[t] = s;
  __syncthreads();
  for (int off = 1; off < 1024; off <<= 1) {
    int v = (t >= off) ? sums[t - off] : 0;
    __syncthreads();
    sums[t] += v;
    __syncthreads();
  }
  const int boff = (t == 0) ? 0 : sums[t - 1];
#pragma unroll
  for (int i = 0; i < 32; ++i) row_ptr[base + i] = boff + local[i];
  if (t == 1023) row_ptr[NN] = sums[1023];
}

// scatter + per-edge softmax weights (hoisted out of agg: one exp per LANE
// here vs 64 redundant per-lane copies inside agg). Same expression order as
// R2's in-agg computation -> bit-identical weights.
__global__ void scatter_w_kernel(const int* __restrict__ ei, const int* __restrict__ row_ptr,
                                 int* __restrict__ cnt2,
                                 const float* __restrict__ al_s, const float* __restrict__ al_d,
                                 int* __restrict__ col, float* __restrict__ w4) {
  int e = blockIdx.x * 256 + threadIdx.x;
  if (e >= ETOT) return;
  int s, d;
  if (e < EE) { s = ei[e]; d = ei[EE + e]; } else { s = e - EE; d = s; }
  int pos = row_ptr[d] + atomicAdd(&cnt2[d], 1);
  col[pos] = s;
  const float4 as = *(const float4*)(al_s + s * NH);
  const float4 ad = *(const float4*)(al_d + d * NH);
  float e0 = as.x + ad.x; e0 = (e0 > 0.f) ? e0 : SLOPE * e0; float w0 = __expf(e0);
  float e1 = as.y + ad.y; e1 = (e1 > 0.f) ? e1 : SLOPE * e1; float w1 = __expf(e1);
  float e2 = as.z + ad.z; e2 = (e2 > 0.f) ? e2 : SLOPE * e2; float w2 = __expf(e2);
  float e3 = as.w + ad.w; e3 = (e3 > 0.f) ? e3 : SLOPE * e3; float w3 = __expf(e3);
  *(float4*)(w4 + (size_t)pos * 4) = make_float4(w0, w1, w2, w3);
}

// ---------------- weighted aggregation (wave per dst node) ----------------
// XCD swizzle kept (R2: FETCH 169->18 MB). Weights precomputed -> inner loop
// is 2 wave-uniform loads + 4 FMA + 4 adds per edge. Accumulation j-order
// identical to R2 -> bit-identical outg.
__global__ __launch_bounds__(256) void agg_kernel(const float* __restrict__ h,
                                                  const float* __restrict__ w4,
                                                  const int* __restrict__ row_ptr,
                                                  const int* __restrict__ col,
                                                  const float* __restrict__ b_gat,
                                                  float* __restrict__ outg) {
  const int lane = threadIdx.x & 63;
  const int xcd = blockIdx.x & 7;
  const int jb  = blockIdx.x >> 3;
  const int n = (xcd * 1024 + jb) * 4 + (threadIdx.x >> 6);
  const int beg = row_ptr[n], end = row_ptr[n + 1];
  float acc0 = 0.f, acc1 = 0.f, acc2 = 0.f, acc3 = 0.f;
  float den0 = 0.f, den1 = 0.f, den2 = 0.f, den3 = 0.f;
  int j = beg;
  for (; j + 1 < end; j += 2) {
    const int sA = col[j];
    const int sB = col[j + 1];
    const float4 wA = *(const float4*)(w4 + (size_t)j * 4);
    const float4 wB = *(const float4*)(w4 + (size_t)(j + 1) * 4);
    const float* hsA = h + (size_t)sA * CC;
    const float* hsB = h + (size_t)sB * CC;
    float hA0 = hsA[lane], hA1 = hsA[64 + lane], hA2 = hsA[128 + lane], hA3 = hsA[192 + lane];
    float hB0 = hsB[lane], hB1 = hsB[64 + lane], hB2 = hsB[128 + lane], hB3 = hsB[192 + lane];
    den0 += wA.x; den1 += wA.y; den2 += wA.z; den3 += wA.w;
    acc0 += wA.x * hA0; acc1 += wA.y * hA1; acc2 += wA.z * hA2; acc3 += wA.w * hA3;
    den0 += wB.x; den1 += wB.y; den2 += wB.z; den3 += wB.w;
    acc0 += wB.x * hB0; acc1 += wB.y * hB1; acc2 += wB.z * hB2; acc3 += wB.w * hB3;
  }
  if (j < end) {
    const int s = col[j];
    const float4 w = *(const float4*)(w4 + (size_t)j * 4);
    const float* hs = h + (size_t)s * CC;
    den0 += w.x; den1 += w.y; den2 += w.z; den3 += w.w;
    acc0 += w.x * hs[lane];
    acc1 += w.y * hs[64 + lane];
    acc2 += w.z * hs[128 + lane];
    acc3 += w.w * hs[192 + lane];
  }
  float* o = outg + (size_t)n * CC;
  o[lane]       = acc0 / den0 + b_gat[lane];
  o[64 + lane]  = acc1 / den1 + b_gat[64 + lane];
  o[128 + lane] = acc2 / den2 + b_gat[128 + lane];
  o[192 + lane] = acc3 / den3 + b_gat[192 + lane];
}

// ---------------- score = tanh(xl . p / ||p||)  (bit-identical) ----------------
__global__ __launch_bounds__(256) void score_kernel(const float* __restrict__ xl,
                                                    const float* __restrict__ p,
                                                    float* __restrict__ score) {
  const int lane = threadIdx.x & 63;
  const int n = blockIdx.x * 4 + (threadIdx.x >> 6);
  float pv = p[lane];
  float pp = pv * pv;
  float dot = xl[(size_t)n * HID + lane] * pv;
#pragma unroll
  for (int off = 32; off > 0; off >>= 1) {
    pp += __shfl_down(pp, off);
    dot += __shfl_down(dot, off);
  }
  if (lane == 0) score[n] = tanhf(dot / sqrtf(pp));
}

// ---------------- per-graph top-k: hybrid bitonic ----------------
__device__ inline unsigned long long shflx64(unsigned long long v, int m) {
  int lo = __shfl_xor((int)(unsigned)v, m, 64);
  int hi = __shfl_xor((int)(unsigned)(v >> 32), m, 64);
  return ((unsigned long long)(unsigned)hi << 32) | (unsigned)lo;
}

__global__ __launch_bounds__(1024) void topk_kernel(const float* __restrict__ score,
                                                    int* __restrict__ perm,
                                                    float* __restrict__ topv,
                                                    int* __restrict__ nmap,
                                                    float* __restrict__ out_batch) {
  __shared__ unsigned long long keys[NPG];
  const int b = blockIdx.x;
  const int t = threadIdx.x;
  unsigned long long v;
  {
    float sc = score[b * NPG + t];
    unsigned u = __float_as_uint(sc);
    u = (u & 0x80000000u) ? ~u : (u | 0x80000000u);
    u = ~u;
    v = ((unsigned long long)u << 32) | (unsigned)t;
  }
  for (int k = 2; k <= NPG; k <<= 1) {
    for (int j = k >> 1; j > 0; j >>= 1) {
      unsigned long long pv;
      if (j >= 64) {
        keys[t] = v;
        __syncthreads();
        pv = keys[t ^ j];
        __syncthreads();
      } else {
        pv = shflx64(v, j);
      }
      bool up = ((t & k) == 0);
      bool small_side = ((t & j) == 0);
      bool take_min = (small_side == up);
      v = take_min ? (v < pv ? v : pv) : (v > pv ? v : pv);
    }
  }
  if (t < KK) {
    int idx = (int)(v & 0xFFFFFFFFull);
    int g = b * NPG + idx;
    int jj = b * KK + t;
    perm[jj] = g;
    topv[jj] = score[g];
    nmap[g] = jj;
    out_batch[jj] = (float)b;
  }
}

// ---------------- gather kept nodes, gate, partial mean/max ----------------
__global__ __launch_bounds__(256) void xp_pool_kernel(const float* __restrict__ xl,
                                                      const int* __restrict__ perm,
                                                      const float* __restrict__ topv,
                                                      float* __restrict__ xp,
                                                      float* __restrict__ partials) {
  __shared__ float sred[16][68];
  __shared__ float mred[16][68];
  const int tid = threadIdx.x;
  const int r = tid >> 4, q = tid & 15;
  const int j = blockIdx.x * 16 + r;
  const int srcn = perm[j];
  const float tv = topv[j];
  float4 val = *(const float4*)(xl + (size_t)srcn * HID + q * 4);
  val.x *= tv; val.y *= tv; val.z *= tv; val.w *= tv;
  *(float4*)(xp + (size_t)j * HID + q * 4) = val;
  sred[r][q * 4 + 0] = val.x; sred[r][q * 4 + 1] = val.y;
  sred[r][q * 4 + 2] = val.z; sred[r][q * 4 + 3] = val.w;
  mred[r][q * 4 + 0] = val.x; mred[r][q * 4 + 1] = val.y;
  mred[r][q * 4 + 2] = val.z; mred[r][q * 4 + 3] = val.w;
  __syncthreads();
  for (int s = 8; s >= 1; s >>= 1) {
    if (r < s) {
#pragma unroll
      for (int i = 0; i < 4; ++i) {
        int c = q * 4 + i;
        sred[r][c] += sred[r + s][c];
        mred[r][c] = fmaxf(mred[r][c], mred[r + s][c]);
      }
    }
    __syncthreads();
  }
  if (r == 0) {
#pragma unroll
    for (int i = 0; i < 4; ++i) {
      int c = q * 4 + i;
      partials[(size_t)blockIdx.x * 128 + c] = sred[0][c];
      partials[(size_t)blockIdx.x * 128 + 64 + c] = mred[0][c];
    }
  }
}

__global__ void pool2_kernel(const float* __restrict__ partials, float* __restrict__ x1) {
  const int b = blockIdx.x;
  const int c = threadIdx.x;
  float s = 0.f, m = -INFINITY;
  for (int pb = 0; pb < 32; ++pb) {
    const float* pp = partials + (size_t)(b * 32 + pb) * 128;
    s += pp[c];
    m = fmaxf(m, pp[64 + c]);
  }
  x1[b * 128 + c] = s * (1.0f / KK);
  x1[b * 128 + 64 + c] = m;
}

// ---------------- edge remap / filter ----------------
__global__ void edge_out_kernel(const int* __restrict__ ei, const float* __restrict__ edge,
                                const int* __restrict__ nmap,
                                float* __restrict__ out_ei, float* __restrict__ out_edge) {
  int e = blockIdx.x * 256 + threadIdx.x;
  if (e >= EE) return;
  int s = ei[e], d = ei[EE + e];
  int ns = nmap[s], nd = nmap[d];
  bool valid = (ns >= 0) && (nd >= 0);
  out_ei[e] = (float)(valid ? ns : -1);
  out_ei[EE + e] = (float)(valid ? nd : -1);
  const float4* ef = (const float4*)(edge + (size_t)e * 8);
  float4 z = make_float4(0.f, 0.f, 0.f, 0.f);
  float4 v0 = valid ? ef[0] : z;
  float4 v1 = valid ? ef[1] : z;
  float4* eo = (float4*)(out_edge + (size_t)e * 8);
  eo[0] = v0; eo[1] = v1;
}

extern "C" void kernel_launch(void* const* d_in, const int* in_sizes, int n_in,
                              void* d_out, int out_size, void* d_ws, size_t ws_size,
                              hipStream_t stream) {
  const float* x      = (const float*)d_in[0];
  const int*   ei     = (const int*)d_in[1];
  const float* edge   = (const float*)d_in[2];
  const float* W      = (const float*)d_in[4];
  const float* a_src  = (const float*)d_in[5];
  const float* a_dst  = (const float*)d_in[6];
  const float* b_gat  = (const float*)d_in[7];
  const float* W_lin  = (const float*)d_in[8];
  const float* b_lin  = (const float*)d_in[9];
  const float* p_pool = (const float*)d_in[10];

  char* ws = (char*)d_ws;
  size_t off = 0;
  auto alloc = [&](size_t bytes) -> void* {
    void* p = ws + off;
    off += (bytes + 255) & ~(size_t)255;
    return p;
  };
  float* h        = (float*)alloc((size_t)NN * CC * 4);
  float* outg     = (float*)alloc((size_t)NN * CC * 4);
  float* xl       = (float*)alloc((size_t)NN * HID * 4);
  float* al_s     = (float*)alloc((size_t)NN * NH * 4);
  float* al_d     = (float*)alloc((size_t)NN * NH * 4);
  float* score    = (float*)alloc((size_t)NN * 4);
  int*   row_ptr  = (int*)alloc((size_t)(NN + 1) * 4);
  int*   cnt      = (int*)alloc((size_t)NN * 4 * 2);   // cnt | cnt2 contiguous
  int*   cnt2     = cnt + NN;
  int*   col      = (int*)alloc((size_t)ETOT * 4);
  float* w4       = (float*)alloc((size_t)ETOT * NH * 4);
  int*   nmap     = (int*)alloc((size_t)NN * 4);
  int*   perm     = (int*)alloc((size_t)BB * KK * 4);
  float* topv     = (float*)alloc((size_t)BB * KK * 4);
  float* partials = (float*)alloc((size_t)1024 * 128 * 4);

  float* out_xp    = (float*)d_out;
  float* out_ei    = out_xp + (size_t)BB * KK * HID;
  float* out_edge  = out_ei + 2 * (size_t)EE;
  float* out_batch = out_edge + (size_t)EE * 8;
  float* out_x1    = out_batch + (size_t)BB * KK;

  hipMemsetAsync(cnt, 0, (size_t)NN * 4 * 2, stream);
  hipMemsetAsync(nmap, 0xFF, (size_t)NN * 4, stream);

  gemm1_kernel<<<dim3(NN / 128, CC / 128), 256, 0, stream>>>(x, W, h);
  al_kernel<<<NN / 4, 256, 0, stream>>>(h, a_src, a_dst, al_s, al_d);
  count_kernel<<<(ETOT + 255) / 256, 256, 0, stream>>>(ei, cnt);
  scan_kernel<<<1, 1024, 0, stream>>>(cnt, row_ptr);
  scatter_w_kernel<<<(ETOT + 255) / 256, 256, 0, stream>>>(ei, row_ptr, cnt2,
                                                           al_s, al_d, col, w4);
  agg_kernel<<<NN / 4, 256, 0, stream>>>(h, w4, row_ptr, col, b_gat, outg);
  gemm2_kernel<<<NN / 128, 256, 0, stream>>>(outg, W_lin, b_lin, xl);
  score_kernel<<<NN / 4, 256, 0, stream>>>(xl, p_pool, score);
  topk_kernel<<<BB, 1024, 0, stream>>>(score, perm, topv, nmap, out_batch);
  xp_pool_kernel<<<BB * KK / 16, 256, 0, stream>>>(xl, perm, topv, out_xp, partials);
  pool2_kernel<<<BB, 64, 0, stream>>>(partials, out_x1);
  edge_out_kernel<<<(EE + 255) / 256, 256, 0, stream>>>(ei, edge, nmap, out_ei, out_edge);
}

// Round 4
// 306.856 us; speedup vs baseline: 1.0021x; 1.0021x over previous
//
#include <hip/hip_runtime.h>
#include <math.h>

#define NN   32768
#define EE   524288
#define ETOT (EE + NN)
#define BB   32
#define NPG  1024
#define EPG  16384          // edges per graph (exact)
#define RPG  17408          // CSR entries per graph = EPG + NPG (self-loops)
#define KK   512
#define INC  128
#define HID  64
#define NH   4
#define CC   256
#define SLOPE 0.2f

// ---------------- GEMM1 + al epilogue ----------------
// 128x64 tile (49.7 KB LDS -> 3 blocks/CU), 4x8 micro-tile. blockIdx.y = head:
// c0 = head*64 covers exactly the columns head `head` needs for al_src/al_dst,
// so the attention logits are computed from in-register acc (no h re-read).
__global__ __launch_bounds__(256) void gemm1_al_kernel(const float* __restrict__ x,
                                                       const float* __restrict__ W,
                                                       const float* __restrict__ a_src,
                                                       const float* __restrict__ a_dst,
                                                       float* __restrict__ h,
                                                       float* __restrict__ al_s,
                                                       float* __restrict__ al_d) {
  __shared__ float As[128][65];
  __shared__ float Bs[64][64];
  const int n0 = blockIdx.x * 128;
  const int head = blockIdx.y;
  const int c0 = head * 64;
  const int tid = threadIdx.x;
  const int rowg = tid >> 3, colg = tid & 7;   // 32 x 8 -> 4x8 micro
  const int lr = tid >> 4, lq = tid & 15;
  float acc[4][8] = {};
  for (int kc = 0; kc < 2; ++kc) {
    const int k0 = kc * 64;
#pragma unroll
    for (int p = 0; p < 8; ++p) {
      int row = p * 16 + lr;
      float4 v = *(const float4*)(x + (size_t)(n0 + row) * INC + k0 + lq * 4);
      As[row][lq * 4 + 0] = v.x; As[row][lq * 4 + 1] = v.y;
      As[row][lq * 4 + 2] = v.z; As[row][lq * 4 + 3] = v.w;
    }
#pragma unroll
    for (int p = 0; p < 4; ++p) {
      int krow = p * 16 + lr;
      *(float4*)(&Bs[krow][lq * 4]) =
          *(const float4*)(W + (size_t)(k0 + krow) * CC + c0 + lq * 4);
    }
    __syncthreads();
#pragma unroll
    for (int k = 0; k < 64; ++k) {
      float4 b0 = *(const float4*)(&Bs[k][colg * 8]);
      float4 b1 = *(const float4*)(&Bs[k][colg * 8 + 4]);
#pragma unroll
      for (int i = 0; i < 4; ++i) {
        float a = As[rowg * 4 + i][k];
        acc[i][0] += a * b0.x; acc[i][1] += a * b0.y;
        acc[i][2] += a * b0.z; acc[i][3] += a * b0.w;
        acc[i][4] += a * b1.x; acc[i][5] += a * b1.y;
        acc[i][6] += a * b1.z; acc[i][7] += a * b1.w;
      }
    }
    __syncthreads();
  }
  const float4 as0 = *(const float4*)(a_src + c0 + colg * 8);
  const float4 as1 = *(const float4*)(a_src + c0 + colg * 8 + 4);
  const float4 ad0 = *(const float4*)(a_dst + c0 + colg * 8);
  const float4 ad1 = *(const float4*)(a_dst + c0 + colg * 8 + 4);
#pragma unroll
  for (int i = 0; i < 4; ++i) {
    float* hp = h + (size_t)(n0 + rowg * 4 + i) * CC + c0 + colg * 8;
    *(float4*)(hp)     = make_float4(acc[i][0], acc[i][1], acc[i][2], acc[i][3]);
    *(float4*)(hp + 4) = make_float4(acc[i][4], acc[i][5], acc[i][6], acc[i][7]);
    float ps = 0.f, pd = 0.f;
    ps += acc[i][0] * as0.x; ps += acc[i][1] * as0.y; ps += acc[i][2] * as0.z; ps += acc[i][3] * as0.w;
    ps += acc[i][4] * as1.x; ps += acc[i][5] * as1.y; ps += acc[i][6] * as1.z; ps += acc[i][7] * as1.w;
    pd += acc[i][0] * ad0.x; pd += acc[i][1] * ad0.y; pd += acc[i][2] * ad0.z; pd += acc[i][3] * ad0.w;
    pd += acc[i][4] * ad1.x; pd += acc[i][5] * ad1.y; pd += acc[i][6] * ad1.z; pd += acc[i][7] * ad1.w;
#pragma unroll
    for (int off = 4; off > 0; off >>= 1) {
      ps += __shfl_down(ps, off, 8);
      pd += __shfl_down(pd, off, 8);
    }
    if (colg == 0) {
      al_s[(n0 + rowg * 4 + i) * NH + head] = ps;
      al_d[(n0 + rowg * 4 + i) * NH + head] = pd;
    }
  }
}

// ---------------- fused CSR build: hist + scan + scatter + weights ----------------
// One block per graph. row_ptr base is statically g*RPG, so the scan is purely
// within-graph (LDS). Self-loops included. Weight expression identical to R3.
__global__ __launch_bounds__(1024) void csr_kernel(const int* __restrict__ ei,
                                                   const float* __restrict__ al_s,
                                                   const float* __restrict__ al_d,
                                                   int* __restrict__ row_ptr,
                                                   int* __restrict__ col,
                                                   float* __restrict__ w4) {
  __shared__ int hist[NPG];
  __shared__ int sums[NPG];
  const int b = blockIdx.x, t = threadIdx.x;
  hist[t] = 0;
  __syncthreads();
  const int ebase = b * EPG;
#pragma unroll
  for (int r = 0; r < 16; ++r) {
    int d = ei[EE + ebase + r * 1024 + t];
    atomicAdd(&hist[d - b * NPG], 1);
  }
  __syncthreads();
  const int cnt_t = hist[t] + 1;                 // + self-loop
  sums[t] = cnt_t;
  __syncthreads();
  for (int off = 1; off < 1024; off <<= 1) {
    int v = (t >= off) ? sums[t - off] : 0;
    __syncthreads();
    sums[t] += v;
    __syncthreads();
  }
  const int excl = sums[t] - cnt_t;
  row_ptr[b * NPG + t] = b * RPG + excl;
  if (b == BB - 1 && t == NPG - 1) row_ptr[NN] = ETOT;
  hist[t] = excl;                                 // running offsets
  __syncthreads();
#pragma unroll
  for (int r = 0; r < 16; ++r) {
    int e = ebase + r * 1024 + t;
    int s = ei[e], d = ei[EE + e];
    int pos = b * RPG + atomicAdd(&hist[d - b * NPG], 1);
    col[pos] = s;
    const float4 as = *(const float4*)(al_s + s * NH);
    const float4 ad = *(const float4*)(al_d + d * NH);
    float e0 = as.x + ad.x; e0 = (e0 > 0.f) ? e0 : SLOPE * e0; float w0 = __expf(e0);
    float e1 = as.y + ad.y; e1 = (e1 > 0.f) ? e1 : SLOPE * e1; float w1 = __expf(e1);
    float e2 = as.z + ad.z; e2 = (e2 > 0.f) ? e2 : SLOPE * e2; float w2 = __expf(e2);
    float e3 = as.w + ad.w; e3 = (e3 > 0.f) ? e3 : SLOPE * e3; float w3 = __expf(e3);
    *(float4*)(w4 + (size_t)pos * 4) = make_float4(w0, w1, w2, w3);
  }
  {
    int g = b * NPG + t;
    int pos = b * RPG + atomicAdd(&hist[t], 1);
    col[pos] = g;
    const float4 as = *(const float4*)(al_s + g * NH);
    const float4 ad = *(const float4*)(al_d + g * NH);
    float e0 = as.x + ad.x; e0 = (e0 > 0.f) ? e0 : SLOPE * e0; float w0 = __expf(e0);
    float e1 = as.y + ad.y; e1 = (e1 > 0.f) ? e1 : SLOPE * e1; float w1 = __expf(e1);
    float e2 = as.z + ad.z; e2 = (e2 > 0.f) ? e2 : SLOPE * e2; float w2 = __expf(e2);
    float e3 = as.w + ad.w; e3 = (e3 > 0.f) ? e3 : SLOPE * e3; float w3 = __expf(e3);
    *(float4*)(w4 + (size_t)pos * 4) = make_float4(w0, w1, w2, w3);
  }
}

// ---------------- weighted aggregation (wave per dst node) ----------------
// Lane-parallel col/w4 fetch + readlane broadcast (SGPR) kills the wave-uniform
// scalar-load latency chain; 2-stage pipeline on the h gather. XCD swizzle kept.
__global__ __launch_bounds__(256) void agg_kernel(const float* __restrict__ h,
                                                  const float* __restrict__ w4,
                                                  const int* __restrict__ row_ptr,
                                                  const int* __restrict__ col,
                                                  const float* __restrict__ b_gat,
                                                  float* __restrict__ outg) {
  const int lane = threadIdx.x & 63;
  const int xcd = blockIdx.x & 7;
  const int jb  = blockIdx.x >> 3;
  const int n = (xcd * 1024 + jb) * 4 + (threadIdx.x >> 6);
  const int beg = row_ptr[n], end = row_ptr[n + 1];
  float acc0 = 0.f, acc1 = 0.f, acc2 = 0.f, acc3 = 0.f;
  float den0 = 0.f, den1 = 0.f, den2 = 0.f, den3 = 0.f;
  for (int base = beg; base < end; base += 64) {
    const int rem = end - base;
    const int cnt = rem < 64 ? rem : 64;
    int cl = 0;
    float4 wl = make_float4(0.f, 0.f, 0.f, 0.f);
    if (lane < cnt) {
      cl = col[base + lane];
      wl = *(const float4*)(w4 + (size_t)(base + lane) * 4);
    }
    int s0 = __builtin_amdgcn_readlane(cl, 0);
    const float* hs = h + (size_t)s0 * CC;
    float h0 = hs[lane], h1 = hs[64 + lane], h2 = hs[128 + lane], h3 = hs[192 + lane];
    for (int i = 0; i < cnt; ++i) {
      float w0 = __int_as_float(__builtin_amdgcn_readlane(__float_as_int(wl.x), i));
      float w1 = __int_as_float(__builtin_amdgcn_readlane(__float_as_int(wl.y), i));
      float w2 = __int_as_float(__builtin_amdgcn_readlane(__float_as_int(wl.z), i));
      float w3 = __int_as_float(__builtin_amdgcn_readlane(__float_as_int(wl.w), i));
      float c0 = h0, c1 = h1, c2 = h2, c3 = h3;
      if (i + 1 < cnt) {
        int sn = __builtin_amdgcn_readlane(cl, i + 1);
        const float* hn = h + (size_t)sn * CC;
        h0 = hn[lane]; h1 = hn[64 + lane]; h2 = hn[128 + lane]; h3 = hn[192 + lane];
      }
      den0 += w0; den1 += w1; den2 += w2; den3 += w3;
      acc0 += w0 * c0; acc1 += w1 * c1; acc2 += w2 * c2; acc3 += w3 * c3;
    }
  }
  float* o = outg + (size_t)n * CC;
  o[lane]       = acc0 / den0 + b_gat[lane];
  o[64 + lane]  = acc1 / den1 + b_gat[64 + lane];
  o[128 + lane] = acc2 / den2 + b_gat[128 + lane];
  o[192 + lane] = acc3 / den3 + b_gat[192 + lane];
}

// ---------------- GEMM2: xl[N,64] = outg[N,256] @ W_lin + b_lin ----------------
__global__ __launch_bounds__(256) void gemm2_kernel(const float* __restrict__ A,
                                                    const float* __restrict__ Wl,
                                                    const float* __restrict__ bl,
                                                    float* __restrict__ xl) {
  __shared__ float As[128][65];
  __shared__ float Bs[64][64];
  const int n0 = blockIdx.x * 128;
  const int tid = threadIdx.x;
  const int rowg = tid >> 3, colg = tid & 7;
  const int lr = tid >> 4, lq = tid & 15;
  float acc[4][8] = {};
  for (int kc = 0; kc < 4; ++kc) {
    const int k0 = kc * 64;
#pragma unroll
    for (int p = 0; p < 8; ++p) {
      int row = p * 16 + lr;
      float4 v = *(const float4*)(A + (size_t)(n0 + row) * CC + k0 + lq * 4);
      As[row][lq * 4 + 0] = v.x; As[row][lq * 4 + 1] = v.y;
      As[row][lq * 4 + 2] = v.z; As[row][lq * 4 + 3] = v.w;
    }
#pragma unroll
    for (int p = 0; p < 4; ++p) {
      int krow = p * 16 + lr;
      *(float4*)(&Bs[krow][lq * 4]) =
          *(const float4*)(Wl + (size_t)(k0 + krow) * HID + lq * 4);
    }
    __syncthreads();
#pragma unroll
    for (int k = 0; k < 64; ++k) {
      float4 b0 = *(const float4*)(&Bs[k][colg * 8]);
      float4 b1 = *(const float4*)(&Bs[k][colg * 8 + 4]);
#pragma unroll
      for (int i = 0; i < 4; ++i) {
        float a = As[rowg * 4 + i][k];
        acc[i][0] += a * b0.x; acc[i][1] += a * b0.y;
        acc[i][2] += a * b0.z; acc[i][3] += a * b0.w;
        acc[i][4] += a * b1.x; acc[i][5] += a * b1.y;
        acc[i][6] += a * b1.z; acc[i][7] += a * b1.w;
      }
    }
    __syncthreads();
  }
  const float4 bv0 = *(const float4*)(bl + colg * 8);
  const float4 bv1 = *(const float4*)(bl + colg * 8 + 4);
#pragma unroll
  for (int i = 0; i < 4; ++i) {
    float* xp = xl + (size_t)(n0 + rowg * 4 + i) * HID + colg * 8;
    *(float4*)(xp)     = make_float4(acc[i][0] + bv0.x, acc[i][1] + bv0.y,
                                     acc[i][2] + bv0.z, acc[i][3] + bv0.w);
    *(float4*)(xp + 4) = make_float4(acc[i][4] + bv1.x, acc[i][5] + bv1.y,
                                     acc[i][6] + bv1.z, acc[i][7] + bv1.w);
  }
}

// ---------------- fused score + top-k + xp + nmap + pool ----------------
__device__ inline unsigned long long shflx64(unsigned long long v, int m) {
  int lo = __shfl_xor((int)(unsigned)v, m, 64);
  int hi = __shfl_xor((int)(unsigned)(v >> 32), m, 64);
  return ((unsigned long long)(unsigned)hi << 32) | (unsigned)lo;
}

__global__ __launch_bounds__(1024) void topk_fused_kernel(const float* __restrict__ xl,
                                                          const float* __restrict__ p,
                                                          float* __restrict__ out_xp,
                                                          int* __restrict__ nmap,
                                                          float* __restrict__ out_batch,
                                                          float* __restrict__ out_x1) {
  __shared__ float scv[NPG];
  __shared__ unsigned long long keys[NPG];
  __shared__ int   pidx[KK];
  __shared__ float tvs[KK];
  __shared__ float ps[16][64];
  __shared__ float pm[16][64];
  const int b = blockIdx.x, t = threadIdx.x;
  // score = tanh(xl.p / ||p||)
  float pp = 0.f, dot = 0.f;
  const float* xr = xl + (size_t)(b * NPG + t) * HID;
#pragma unroll
  for (int q = 0; q < 16; ++q) {
    float4 w = *(const float4*)(p + q * 4);
    float4 v = *(const float4*)(xr + q * 4);
    pp += w.x * w.x; pp += w.y * w.y; pp += w.z * w.z; pp += w.w * w.w;
    dot += v.x * w.x; dot += v.y * w.y; dot += v.z * w.z; dot += v.w * w.w;
  }
  float sc = tanhf(dot / sqrtf(pp));
  scv[t] = sc;
  nmap[b * NPG + t] = -1;
  unsigned long long v;
  {
    unsigned u = __float_as_uint(sc);
    u = (u & 0x80000000u) ? ~u : (u | 0x80000000u);
    u = ~u;                                        // descending by score
    v = ((unsigned long long)u << 32) | (unsigned)t;  // asc index tiebreak
  }
  __syncthreads();
  for (int k = 2; k <= NPG; k <<= 1) {
    for (int j = k >> 1; j > 0; j >>= 1) {
      unsigned long long pv;
      if (j >= 64) {
        keys[t] = v;
        __syncthreads();
        pv = keys[t ^ j];
        __syncthreads();
      } else {
        pv = shflx64(v, j);
      }
      bool up = ((t & k) == 0);
      bool small_side = ((t & j) == 0);
      bool take_min = (small_side == up);
      v = take_min ? (v < pv ? v : pv) : (v > pv ? v : pv);
    }
  }
  if (t < KK) {
    int idx = (int)(v & 0xFFFFFFFFull);
    pidx[t] = idx;
    tvs[t] = scv[idx];
    nmap[b * NPG + idx] = b * KK + t;
    out_batch[b * KK + t] = (float)b;
  }
  __syncthreads();
  // gather + gate kept rows
  for (int u2 = t; u2 < KK * 16; u2 += 1024) {
    int row = u2 >> 4, q = u2 & 15;
    int g = b * NPG + pidx[row];
    float4 vv = *(const float4*)(xl + (size_t)g * HID + q * 4);
    float tv = tvs[row];
    vv.x *= tv; vv.y *= tv; vv.z *= tv; vv.w *= tv;
    *(float4*)(out_xp + (size_t)(b * KK + row) * HID + q * 4) = vv;
  }
  __syncthreads();
  // mean/max pool over the block's own xp writes (same CU -> coherent)
  const int c = t & 63, rg = t >> 6;
  float s = 0.f, m = -INFINITY;
  for (int row = rg; row < KK; row += 16) {
    float vv = out_xp[(size_t)(b * KK + row) * HID + c];
    s += vv; m = fmaxf(m, vv);
  }
  ps[rg][c] = s; pm[rg][c] = m;
  __syncthreads();
  if (t < 64) {
    float st = 0.f, mt = -INFINITY;
#pragma unroll
    for (int g2 = 0; g2 < 16; ++g2) { st += ps[g2][t]; mt = fmaxf(mt, pm[g2][t]); }
    out_x1[b * 128 + t] = st * (1.0f / KK);
    out_x1[b * 128 + 64 + t] = mt;
  }
}

// ---------------- edge remap / filter ----------------
__global__ void edge_out_kernel(const int* __restrict__ ei, const float* __restrict__ edge,
                                const int* __restrict__ nmap,
                                float* __restrict__ out_ei, float* __restrict__ out_edge) {
  int e = blockIdx.x * 256 + threadIdx.x;
  if (e >= EE) return;
  int s = ei[e], d = ei[EE + e];
  int ns = nmap[s], nd = nmap[d];
  bool valid = (ns >= 0) && (nd >= 0);
  out_ei[e] = (float)(valid ? ns : -1);
  out_ei[EE + e] = (float)(valid ? nd : -1);
  const float4* ef = (const float4*)(edge + (size_t)e * 8);
  float4 z = make_float4(0.f, 0.f, 0.f, 0.f);
  float4 v0 = valid ? ef[0] : z;
  float4 v1 = valid ? ef[1] : z;
  float4* eo = (float4*)(out_edge + (size_t)e * 8);
  eo[0] = v0; eo[1] = v1;
}

extern "C" void kernel_launch(void* const* d_in, const int* in_sizes, int n_in,
                              void* d_out, int out_size, void* d_ws, size_t ws_size,
                              hipStream_t stream) {
  const float* x      = (const float*)d_in[0];
  const int*   ei     = (const int*)d_in[1];
  const float* edge   = (const float*)d_in[2];
  const float* W      = (const float*)d_in[4];
  const float* a_src  = (const float*)d_in[5];
  const float* a_dst  = (const float*)d_in[6];
  const float* b_gat  = (const float*)d_in[7];
  const float* W_lin  = (const float*)d_in[8];
  const float* b_lin  = (const float*)d_in[9];
  const float* p_pool = (const float*)d_in[10];

  char* ws = (char*)d_ws;
  size_t off = 0;
  auto alloc = [&](size_t bytes) -> void* {
    void* p = ws + off;
    off += (bytes + 255) & ~(size_t)255;
    return p;
  };
  float* h       = (float*)alloc((size_t)NN * CC * 4);
  float* outg    = (float*)alloc((size_t)NN * CC * 4);
  float* xl      = (float*)alloc((size_t)NN * HID * 4);
  float* al_s    = (float*)alloc((size_t)NN * NH * 4);
  float* al_d    = (float*)alloc((size_t)NN * NH * 4);
  int*   row_ptr = (int*)alloc((size_t)(NN + 1) * 4);
  int*   col     = (int*)alloc((size_t)ETOT * 4);
  float* w4      = (float*)alloc((size_t)ETOT * NH * 4);
  int*   nmap    = (int*)alloc((size_t)NN * 4);

  float* out_xp    = (float*)d_out;
  float* out_ei    = out_xp + (size_t)BB * KK * HID;
  float* out_edge  = out_ei + 2 * (size_t)EE;
  float* out_batch = out_edge + (size_t)EE * 8;
  float* out_x1    = out_batch + (size_t)BB * KK;

  gemm1_al_kernel<<<dim3(NN / 128, NH), 256, 0, stream>>>(x, W, a_src, a_dst,
                                                          h, al_s, al_d);
  csr_kernel<<<BB, 1024, 0, stream>>>(ei, al_s, al_d, row_ptr, col, w4);
  agg_kernel<<<NN / 4, 256, 0, stream>>>(h, w4, row_ptr, col, b_gat, outg);
  gemm2_kernel<<<NN / 128, 256, 0, stream>>>(outg, W_lin, b_lin, xl);
  topk_fused_kernel<<<BB, 1024, 0, stream>>>(xl, p_pool, out_xp, nmap,
                                             out_batch, out_x1);
  edge_out_kernel<<<(EE + 255) / 256, 256, 0, stream>>>(ei, edge, nmap, out_ei, out_edge);
}

// Round 5
// 267.267 us; speedup vs baseline: 1.1506x; 1.1481x over previous
//
#include <hip/hip_runtime.h>
#include <math.h>

#define NN   32768
#define EE   524288
#define ETOT (EE + NN)
#define BB   32
#define NPG  1024
#define EPG  16384
#define RPG  17408          // CSR entries per graph = EPG + NPG (self-loops)
#define KK   512
#define INC  128
#define HID  64
#define NH   4
#define CC   256
#define SLOPE 0.2f

// ---------------- GEMM1 + al epilogue ----------------
// 128x64 tile, 4x8 micro-tile, blockIdx.y = head; attention logits computed
// from in-register acc (no h re-read).
__global__ __launch_bounds__(256) void gemm1_al_kernel(const float* __restrict__ x,
                                                       const float* __restrict__ W,
                                                       const float* __restrict__ a_src,
                                                       const float* __restrict__ a_dst,
                                                       float* __restrict__ h,
                                                       float* __restrict__ al_s,
                                                       float* __restrict__ al_d) {
  __shared__ float As[128][65];
  __shared__ float Bs[64][64];
  const int n0 = blockIdx.x * 128;
  const int head = blockIdx.y;
  const int c0 = head * 64;
  const int tid = threadIdx.x;
  const int rowg = tid >> 3, colg = tid & 7;
  const int lr = tid >> 4, lq = tid & 15;
  float acc[4][8] = {};
  for (int kc = 0; kc < 2; ++kc) {
    const int k0 = kc * 64;
#pragma unroll
    for (int p = 0; p < 8; ++p) {
      int row = p * 16 + lr;
      float4 v = *(const float4*)(x + (size_t)(n0 + row) * INC + k0 + lq * 4);
      As[row][lq * 4 + 0] = v.x; As[row][lq * 4 + 1] = v.y;
      As[row][lq * 4 + 2] = v.z; As[row][lq * 4 + 3] = v.w;
    }
#pragma unroll
    for (int p = 0; p < 4; ++p) {
      int krow = p * 16 + lr;
      *(float4*)(&Bs[krow][lq * 4]) =
          *(const float4*)(W + (size_t)(k0 + krow) * CC + c0 + lq * 4);
    }
    __syncthreads();
#pragma unroll
    for (int k = 0; k < 64; ++k) {
      float4 b0 = *(const float4*)(&Bs[k][colg * 8]);
      float4 b1 = *(const float4*)(&Bs[k][colg * 8 + 4]);
#pragma unroll
      for (int i = 0; i < 4; ++i) {
        float a = As[rowg * 4 + i][k];
        acc[i][0] += a * b0.x; acc[i][1] += a * b0.y;
        acc[i][2] += a * b0.z; acc[i][3] += a * b0.w;
        acc[i][4] += a * b1.x; acc[i][5] += a * b1.y;
        acc[i][6] += a * b1.z; acc[i][7] += a * b1.w;
      }
    }
    __syncthreads();
  }
  const float4 as0 = *(const float4*)(a_src + c0 + colg * 8);
  const float4 as1 = *(const float4*)(a_src + c0 + colg * 8 + 4);
  const float4 ad0 = *(const float4*)(a_dst + c0 + colg * 8);
  const float4 ad1 = *(const float4*)(a_dst + c0 + colg * 8 + 4);
#pragma unroll
  for (int i = 0; i < 4; ++i) {
    float* hp = h + (size_t)(n0 + rowg * 4 + i) * CC + c0 + colg * 8;
    *(float4*)(hp)     = make_float4(acc[i][0], acc[i][1], acc[i][2], acc[i][3]);
    *(float4*)(hp + 4) = make_float4(acc[i][4], acc[i][5], acc[i][6], acc[i][7]);
    float ps = 0.f, pd = 0.f;
    ps += acc[i][0] * as0.x; ps += acc[i][1] * as0.y; ps += acc[i][2] * as0.z; ps += acc[i][3] * as0.w;
    ps += acc[i][4] * as1.x; ps += acc[i][5] * as1.y; ps += acc[i][6] * as1.z; ps += acc[i][7] * as1.w;
    pd += acc[i][0] * ad0.x; pd += acc[i][1] * ad0.y; pd += acc[i][2] * ad0.z; pd += acc[i][3] * ad0.w;
    pd += acc[i][4] * ad1.x; pd += acc[i][5] * ad1.y; pd += acc[i][6] * ad1.z; pd += acc[i][7] * ad1.w;
#pragma unroll
    for (int off = 4; off > 0; off >>= 1) {
      ps += __shfl_down(ps, off, 8);
      pd += __shfl_down(pd, off, 8);
    }
    if (colg == 0) {
      al_s[(n0 + rowg * 4 + i) * NH + head] = ps;
      al_d[(n0 + rowg * 4 + i) * NH + head] = pd;
    }
  }
}

// ---------------- CSR build: edge-parallel, global atomics ----------------
__global__ void count_kernel(const int* __restrict__ ei, int* __restrict__ cnt) {
  int e = blockIdx.x * 256 + threadIdx.x;
  if (e >= EE) return;
  atomicAdd(&cnt[ei[EE + e]], 1);
}

// per-graph LDS scan; also initializes the scatter cursor (cnt2 = row_ptr).
__global__ __launch_bounds__(1024) void scan_g_kernel(const int* __restrict__ cnt,
                                                      int* __restrict__ row_ptr,
                                                      int* __restrict__ cnt2) {
  __shared__ int sums[NPG];
  const int b = blockIdx.x, t = threadIdx.x;
  const int c = cnt[b * NPG + t] + 1;            // + self-loop
  sums[t] = c;
  __syncthreads();
  for (int off = 1; off < NPG; off <<= 1) {
    int v = (t >= off) ? sums[t - off] : 0;
    __syncthreads();
    sums[t] += v;
    __syncthreads();
  }
  const int pos = b * RPG + sums[t] - c;
  row_ptr[b * NPG + t] = pos;
  cnt2[b * NPG + t] = pos;
  if (b == 0 && t == 0) row_ptr[NN] = ETOT;
}

__global__ void scatter_w_kernel(const int* __restrict__ ei,
                                 int* __restrict__ cnt2,
                                 const float* __restrict__ al_s,
                                 const float* __restrict__ al_d,
                                 int* __restrict__ col, float* __restrict__ w4) {
  int e = blockIdx.x * 256 + threadIdx.x;
  if (e >= ETOT) return;
  int s, d;
  if (e < EE) { s = ei[e]; d = ei[EE + e]; } else { s = e - EE; d = s; }
  int pos = atomicAdd(&cnt2[d], 1);
  col[pos] = s;
  const float4 as = *(const float4*)(al_s + s * NH);
  const float4 ad = *(const float4*)(al_d + d * NH);
  float e0 = as.x + ad.x; e0 = (e0 > 0.f) ? e0 : SLOPE * e0; float w0 = __expf(e0);
  float e1 = as.y + ad.y; e1 = (e1 > 0.f) ? e1 : SLOPE * e1; float w1 = __expf(e1);
  float e2 = as.z + ad.z; e2 = (e2 > 0.f) ? e2 : SLOPE * e2; float w2 = __expf(e2);
  float e3 = as.w + ad.w; e3 = (e3 > 0.f) ? e3 : SLOPE * e3; float w3 = __expf(e3);
  *(float4*)(w4 + (size_t)pos * 4) = make_float4(w0, w1, w2, w3);
}

// ---------------- weighted aggregation (wave per dst node) ----------------
// Lane l owns channels 4l..4l+3 (head = l>>4): the h gather is ONE dwordx4 per
// edge per lane (coalesced 1 KB/wave). Edge metadata staged per-wave into LDS
// (wave-coherent region -> no barrier; per-edge weight is a 16-lane broadcast
// ds_read). 2-stage prefetch on the h rows. XCD swizzle kept.
__global__ __launch_bounds__(256) void agg_kernel(const float* __restrict__ h,
                                                  const float* __restrict__ w4,
                                                  const int* __restrict__ row_ptr,
                                                  const int* __restrict__ col,
                                                  const float* __restrict__ b_gat,
                                                  float* __restrict__ outg) {
  __shared__ float wsh[4][256];
  __shared__ int   csh[4][64];
  const int lane = threadIdx.x & 63;
  const int wv = threadIdx.x >> 6;
  const int hq = lane >> 4;                       // head for this lane
  const int xcd = blockIdx.x & 7;
  const int jb  = blockIdx.x >> 3;
  const int n = (xcd * 1024 + jb) * 4 + wv;
  const int beg = row_ptr[n], end = row_ptr[n + 1];
  float ax = 0.f, ay = 0.f, az = 0.f, aw = 0.f, den = 0.f;
  for (int base = beg; base < end; base += 64) {
    const int rem = end - base;
    const int cnt = rem < 64 ? rem : 64;
    if (lane < cnt) {
      csh[wv][lane] = col[base + lane];
      *(float4*)(&wsh[wv][lane * 4]) = *(const float4*)(w4 + (size_t)(base + lane) * 4);
    }
    // wave-coherent LDS: all lanes wrote above before any lane reads below
    int s0 = csh[wv][0];
    float4 hc = *(const float4*)(h + (size_t)s0 * CC + lane * 4);
    for (int i = 0; i < cnt; ++i) {
      float w = wsh[wv][i * 4 + hq];
      float4 cur = hc;
      if (i + 1 < cnt) {
        int sn = csh[wv][i + 1];
        hc = *(const float4*)(h + (size_t)sn * CC + lane * 4);
      }
      den += w;
      ax += w * cur.x; ay += w * cur.y; az += w * cur.z; aw += w * cur.w;
    }
  }
  const float4 bg = *(const float4*)(b_gat + lane * 4);
  float4 o = make_float4(ax / den + bg.x, ay / den + bg.y,
                         az / den + bg.z, aw / den + bg.w);
  *(float4*)(outg + (size_t)n * CC + lane * 4) = o;
}

// ---------------- GEMM2: xl[N,64] = outg[N,256] @ W_lin + b_lin ----------------
__global__ __launch_bounds__(256) void gemm2_kernel(const float* __restrict__ A,
                                                    const float* __restrict__ Wl,
                                                    const float* __restrict__ bl,
                                                    float* __restrict__ xl) {
  __shared__ float As[128][65];
  __shared__ float Bs[64][64];
  const int n0 = blockIdx.x * 128;
  const int tid = threadIdx.x;
  const int rowg = tid >> 3, colg = tid & 7;
  const int lr = tid >> 4, lq = tid & 15;
  float acc[4][8] = {};
  for (int kc = 0; kc < 4; ++kc) {
    const int k0 = kc * 64;
#pragma unroll
    for (int p = 0; p < 8; ++p) {
      int row = p * 16 + lr;
      float4 v = *(const float4*)(A + (size_t)(n0 + row) * CC + k0 + lq * 4);
      As[row][lq * 4 + 0] = v.x; As[row][lq * 4 + 1] = v.y;
      As[row][lq * 4 + 2] = v.z; As[row][lq * 4 + 3] = v.w;
    }
#pragma unroll
    for (int p = 0; p < 4; ++p) {
      int krow = p * 16 + lr;
      *(float4*)(&Bs[krow][lq * 4]) =
          *(const float4*)(Wl + (size_t)(k0 + krow) * HID + lq * 4);
    }
    __syncthreads();
#pragma unroll
    for (int k = 0; k < 64; ++k) {
      float4 b0 = *(const float4*)(&Bs[k][colg * 8]);
      float4 b1 = *(const float4*)(&Bs[k][colg * 8 + 4]);
#pragma unroll
      for (int i = 0; i < 4; ++i) {
        float a = As[rowg * 4 + i][k];
        acc[i][0] += a * b0.x; acc[i][1] += a * b0.y;
        acc[i][2] += a * b0.z; acc[i][3] += a * b0.w;
        acc[i][4] += a * b1.x; acc[i][5] += a * b1.y;
        acc[i][6] += a * b1.z; acc[i][7] += a * b1.w;
      }
    }
    __syncthreads();
  }
  const float4 bv0 = *(const float4*)(bl + colg * 8);
  const float4 bv1 = *(const float4*)(bl + colg * 8 + 4);
#pragma unroll
  for (int i = 0; i < 4; ++i) {
    float* xp = xl + (size_t)(n0 + rowg * 4 + i) * HID + colg * 8;
    *(float4*)(xp)     = make_float4(acc[i][0] + bv0.x, acc[i][1] + bv0.y,
                                     acc[i][2] + bv0.z, acc[i][3] + bv0.w);
    *(float4*)(xp + 4) = make_float4(acc[i][4] + bv1.x, acc[i][5] + bv1.y,
                                     acc[i][6] + bv1.z, acc[i][7] + bv1.w);
  }
}

// ---------------- fused score + top-k + xp + nmap + pool ----------------
__device__ inline unsigned long long shflx64(unsigned long long v, int m) {
  int lo = __shfl_xor((int)(unsigned)v, m, 64);
  int hi = __shfl_xor((int)(unsigned)(v >> 32), m, 64);
  return ((unsigned long long)(unsigned)hi << 32) | (unsigned)lo;
}

__global__ __launch_bounds__(1024) void topk_fused_kernel(const float* __restrict__ xl,
                                                          const float* __restrict__ p,
                                                          float* __restrict__ out_xp,
                                                          int* __restrict__ nmap,
                                                          float* __restrict__ out_batch,
                                                          float* __restrict__ out_x1) {
  __shared__ float scv[NPG];
  __shared__ unsigned long long keys[NPG];
  __shared__ int   pidx[KK];
  __shared__ float tvs[KK];
  __shared__ float ps[16][64];
  __shared__ float pm[16][64];
  const int b = blockIdx.x, t = threadIdx.x;
  float pp = 0.f, dot = 0.f;
  const float* xr = xl + (size_t)(b * NPG + t) * HID;
#pragma unroll
  for (int q = 0; q < 16; ++q) {
    float4 w = *(const float4*)(p + q * 4);
    float4 v = *(const float4*)(xr + q * 4);
    pp += w.x * w.x; pp += w.y * w.y; pp += w.z * w.z; pp += w.w * w.w;
    dot += v.x * w.x; dot += v.y * w.y; dot += v.z * w.z; dot += v.w * w.w;
  }
  float sc = tanhf(dot / sqrtf(pp));
  scv[t] = sc;
  nmap[b * NPG + t] = -1;
  unsigned long long v;
  {
    unsigned u = __float_as_uint(sc);
    u = (u & 0x80000000u) ? ~u : (u | 0x80000000u);
    u = ~u;
    v = ((unsigned long long)u << 32) | (unsigned)t;
  }
  __syncthreads();
  for (int k = 2; k <= NPG; k <<= 1) {
    for (int j = k >> 1; j > 0; j >>= 1) {
      unsigned long long pv;
      if (j >= 64) {
        keys[t] = v;
        __syncthreads();
        pv = keys[t ^ j];
        __syncthreads();
      } else {
        pv = shflx64(v, j);
      }
      bool up = ((t & k) == 0);
      bool small_side = ((t & j) == 0);
      bool take_min = (small_side == up);
      v = take_min ? (v < pv ? v : pv) : (v > pv ? v : pv);
    }
  }
  if (t < KK) {
    int idx = (int)(v & 0xFFFFFFFFull);
    pidx[t] = idx;
    tvs[t] = scv[idx];
    nmap[b * NPG + idx] = b * KK + t;
    out_batch[b * KK + t] = (float)b;
  }
  __syncthreads();
  for (int u2 = t; u2 < KK * 16; u2 += 1024) {
    int row = u2 >> 4, q = u2 & 15;
    int g = b * NPG + pidx[row];
    float4 vv = *(const float4*)(xl + (size_t)g * HID + q * 4);
    float tv = tvs[row];
    vv.x *= tv; vv.y *= tv; vv.z *= tv; vv.w *= tv;
    *(float4*)(out_xp + (size_t)(b * KK + row) * HID + q * 4) = vv;
  }
  __syncthreads();
  const int c = t & 63, rg = t >> 6;
  float s = 0.f, m = -INFINITY;
  for (int row = rg; row < KK; row += 16) {
    float vv = out_xp[(size_t)(b * KK + row) * HID + c];
    s += vv; m = fmaxf(m, vv);
  }
  ps[rg][c] = s; pm[rg][c] = m;
  __syncthreads();
  if (t < 64) {
    float st = 0.f, mt = -INFINITY;
#pragma unroll
    for (int g2 = 0; g2 < 16; ++g2) { st += ps[g2][t]; mt = fmaxf(mt, pm[g2][t]); }
    out_x1[b * 128 + t] = st * (1.0f / KK);
    out_x1[b * 128 + 64 + t] = mt;
  }
}

// ---------------- edge remap / filter ----------------
__global__ void edge_out_kernel(const int* __restrict__ ei, const float* __restrict__ edge,
                                const int* __restrict__ nmap,
                                float* __restrict__ out_ei, float* __restrict__ out_edge) {
  int e = blockIdx.x * 256 + threadIdx.x;
  if (e >= EE) return;
  int s = ei[e], d = ei[EE + e];
  int ns = nmap[s], nd = nmap[d];
  bool valid = (ns >= 0) && (nd >= 0);
  out_ei[e] = (float)(valid ? ns : -1);
  out_ei[EE + e] = (float)(valid ? nd : -1);
  const float4* ef = (const float4*)(edge + (size_t)e * 8);
  float4 z = make_float4(0.f, 0.f, 0.f, 0.f);
  float4 v0 = valid ? ef[0] : z;
  float4 v1 = valid ? ef[1] : z;
  float4* eo = (float4*)(out_edge + (size_t)e * 8);
  eo[0] = v0; eo[1] = v1;
}

extern "C" void kernel_launch(void* const* d_in, const int* in_sizes, int n_in,
                              void* d_out, int out_size, void* d_ws, size_t ws_size,
                              hipStream_t stream) {
  const float* x      = (const float*)d_in[0];
  const int*   ei     = (const int*)d_in[1];
  const float* edge   = (const float*)d_in[2];
  const float* W      = (const float*)d_in[4];
  const float* a_src  = (const float*)d_in[5];
  const float* a_dst  = (const float*)d_in[6];
  const float* b_gat  = (const float*)d_in[7];
  const float* W_lin  = (const float*)d_in[8];
  const float* b_lin  = (const float*)d_in[9];
  const float* p_pool = (const float*)d_in[10];

  char* ws = (char*)d_ws;
  size_t off = 0;
  auto alloc = [&](size_t bytes) -> void* {
    void* p = ws + off;
    off += (bytes + 255) & ~(size_t)255;
    return p;
  };
  float* h       = (float*)alloc((size_t)NN * CC * 4);
  float* outg    = (float*)alloc((size_t)NN * CC * 4);
  float* xl      = (float*)alloc((size_t)NN * HID * 4);
  float* al_s    = (float*)alloc((size_t)NN * NH * 4);
  float* al_d    = (float*)alloc((size_t)NN * NH * 4);
  int*   row_ptr = (int*)alloc((size_t)(NN + 1) * 4);
  int*   cnt     = (int*)alloc((size_t)NN * 4);
  int*   cnt2    = (int*)alloc((size_t)NN * 4);
  int*   col     = (int*)alloc((size_t)ETOT * 4);
  float* w4      = (float*)alloc((size_t)ETOT * NH * 4);
  int*   nmap    = (int*)alloc((size_t)NN * 4);

  float* out_xp    = (float*)d_out;
  float* out_ei    = out_xp + (size_t)BB * KK * HID;
  float* out_edge  = out_ei + 2 * (size_t)EE;
  float* out_batch = out_edge + (size_t)EE * 8;
  float* out_x1    = out_batch + (size_t)BB * KK;

  hipMemsetAsync(cnt, 0, (size_t)NN * 4, stream);

  gemm1_al_kernel<<<dim3(NN / 128, NH), 256, 0, stream>>>(x, W, a_src, a_dst,
                                                          h, al_s, al_d);
  count_kernel<<<EE / 256, 256, 0, stream>>>(ei, cnt);
  scan_g_kernel<<<BB, 1024, 0, stream>>>(cnt, row_ptr, cnt2);
  scatter_w_kernel<<<(ETOT + 255) / 256, 256, 0, stream>>>(ei, cnt2, al_s, al_d, col, w4);
  agg_kernel<<<NN / 4, 256, 0, stream>>>(h, w4, row_ptr, col, b_gat, outg);
  gemm2_kernel<<<NN / 128, 256, 0, stream>>>(outg, W_lin, b_lin, xl);
  topk_fused_kernel<<<BB, 1024, 0, stream>>>(xl, p_pool, out_xp, nmap,
                                             out_batch, out_x1);
  edge_out_kernel<<<(EE + 255) / 256, 256, 0, stream>>>(ei, edge, nmap, out_ei, out_edge);
}